// Round 7
// baseline (455.400 us; speedup 1.0000x reference)
//
#include <hip/hip_runtime.h>
#include <stdint.h>

// Problem constants (B, LQ, LK, D fixed by the reference)
#define NB    32
#define SLQ   2048
#define SLK   2048
#define DD    128
#define QTILE 128          // q rows per workgroup
#define KVB   64           // keys per block iteration
#define NKB   (SLK / KVB)  // 32

// 8 waves/block: wave (qg, th): qg = q-row group (32 rows), th = key-half for
// QK^T/softmax AND d-half for PV. P is exchanged between th-pairs via LDS.

typedef __attribute__((ext_vector_type(8)))  short    bf16x8;
typedef __attribute__((ext_vector_type(16))) float    f32x16;
typedef __attribute__((ext_vector_type(4)))  float    f32x4v;
typedef __attribute__((ext_vector_type(4)))  uint32_t u32x4;
typedef __attribute__((ext_vector_type(2)))  uint32_t u32x2;

union FragU { uint32_t u[4]; bf16x8 v; };

// HW packed f32->bf16 (RNE), 1 inst per pair
__device__ __forceinline__ uint32_t cvtpk(float lo, float hi) {
    uint32_t r;
    asm("v_cvt_pk_bf16_f32 %0, %1, %2" : "=v"(r) : "v"(lo), "v"(hi));
    return r;
}
// 16 mask bytes (0/1) -> 16 bits
__device__ __forceinline__ uint32_t pack16(u32x4 a) {
    uint32_t r0 = (((a.x & 0x01010101u) * 0x01020408u) >> 24) & 0xFu;
    uint32_t r1 = (((a.y & 0x01010101u) * 0x01020408u) >> 24) & 0xFu;
    uint32_t r2 = (((a.z & 0x01010101u) * 0x01020408u) >> 24) & 0xFu;
    uint32_t r3 = (((a.w & 0x01010101u) * 0x01020408u) >> 24) & 0xFu;
    return r0 | (r1 << 4) | (r2 << 8) | (r3 << 12);
}
#if __has_builtin(__builtin_amdgcn_exp2f)
#define EXP2(x) __builtin_amdgcn_exp2f(x)
#else
#define EXP2(x) exp2f(x)
#endif

__global__ __launch_bounds__(512, 4)
void attn_fwd(const float* __restrict__ qp, const float* __restrict__ kp,
              const float* __restrict__ vp, const void* __restrict__ mp,
              float* __restrict__ op)
{
    // 16 + 16 + 1 + 16 KB = 49 KB -> 2 blocks/CU (grid = 2/CU), 16 waves/CU
    __shared__ short    k_lds[KVB * DD];    // [64 key][128 d] bf16, 16B-XOR swizzle
    __shared__ short    vt_lds[DD * KVB];   // [128 d][64 key] bf16, 8B-XOR swizzle
    __shared__ uint16_t m_lds[QTILE * 4];   // [128 q][4 x 16 key-bits]
    __shared__ uint32_t p_lds[8 * 64 * 8];  // [wave][row=hi2*32+q][8 dwords], slot-swizzled
    __shared__ int      det_flags;

    const int tid  = threadIdx.x;
    const int lane = tid & 63;
    const int wv   = tid >> 6;   // 0..7
    const int qg   = wv >> 1;    // q-row group 0..3
    const int th   = wv & 1;     // key-half (QK^T/SM) and d-half (PV)
    const int l31  = lane & 31;
    const int hi2  = lane >> 5;  // 0/1
    const int sswz = (l31 >> 2) & 3;  // P-slot swizzle (conflict-free derivation R6)

    // XCD-chunked swizzle: 512 WGs, 8 XCDs -> each XCD gets 64 consecutive work ids
    const int bid = blockIdx.x;
    const int wg  = (bid & 7) * 64 + (bid >> 3);
    const int b   = wg >> 4;            // batch
    const int q0  = (wg & 15) * QTILE;  // q tile origin

    // ---- mask dtype self-detection (R2 FETCH proved u8; keep as safety) ----
    if (tid == 0) det_flags = 0;
    __syncthreads();
    {
        const u32x4 w = *(const u32x4*)((const char*)mp + tid * 16);
        const uint32_t any_hi    = (w.x | w.y | w.z | w.w) & 0xFFFFFF00u;
        const uint32_t any_mod84 = (w.y | w.w) & 0xFFu;
        const int f = (any_hi ? 1 : 0) | (any_mod84 ? 2 : 0);
        if (f) atomicOr(&det_flags, f);
    }
    __syncthreads();
    const int mflags = det_flags;
    const int mmode  = (mflags & 1) ? 0 : ((mflags & 2) ? 1 : 2);  // 0=u8, 1=i32, 2=i64

    // scale = log2(e)/sqrt(128): scores land in log2 units -> softmax is bare v_exp
    const float qsc = 0.12751744846458246f;

    // ---- persistent Q fragments (B-operand of swapped QK^T), full D range ----
    bf16x8 qf[8];
    {
        const float* qrow = qp + ((size_t)b * SLQ + (size_t)(q0 + qg * 32 + l31)) * DD;
        #pragma unroll
        for (int ks = 0; ks < 8; ++ks) {
            f32x4v x0 = *(const f32x4v*)(qrow + 16 * ks + 8 * hi2);
            f32x4v x1 = *(const f32x4v*)(qrow + 16 * ks + 8 * hi2 + 4);
            FragU f;
            f.u[0] = cvtpk(x0.x * qsc, x0.y * qsc);
            f.u[1] = cvtpk(x0.z * qsc, x0.w * qsc);
            f.u[2] = cvtpk(x1.x * qsc, x1.y * qsc);
            f.u[3] = cvtpk(x1.z * qsc, x1.w * qsc);
            qf[ks] = f.v;
        }
    }

    // per-wave output: O[32 q of qg][64 d of th] -> 2 x f32x16
    f32x16 oacc[2];
    #pragma unroll
    for (int i = 0; i < 2; ++i)
        #pragma unroll
        for (int j = 0; j < 16; ++j) oacc[i][j] = 0.0f;
    float psum = 0.0f;  // masked-exp sum over this wave's key half

    const float* kb0 = kp + (size_t)b * SLK * DD;
    const float* vb0 = vp + (size_t)b * SLK * DD;
    const size_t mrow0 = ((size_t)b * SLQ + q0) * SLK;

    // ---- prefetch registers (T14), split across 512 threads ----
    f32x4v kreg[4];
    float  vreg[16];
    u32x4  mreg;

    const int vd  = tid & 127;       // d-row staged for V^T
    const int vg  = tid >> 7;        // 0..3 -> keys 16*vg..+15
    const int swv = (vd & 15) << 3;  // V^T 8B-granular XOR
    const int mqq = tid >> 2;        // mask q row
    const int mpt = tid & 3;         // mask 16-key part

    #define LOAD_TILE(KB)                                                         \
        do {                                                                      \
            const int k0_ = (KB) * KVB;                                           \
            const float* kbase_ = kb0 + (size_t)k0_ * DD;                         \
            _Pragma("unroll")                                                     \
            for (int j = 0; j < 4; ++j)                                           \
                kreg[j] = *(const f32x4v*)(kbase_ + (j * 512 + tid) * 4);         \
            const float* vcol_ = vb0 + ((size_t)k0_ + 16 * vg) * DD + vd;         \
            _Pragma("unroll")                                                     \
            for (int jj = 0; jj < 16; ++jj) vreg[jj] = vcol_[(size_t)jj * DD];    \
            if (mmode == 0) {                                                     \
                mreg = *(const u32x4*)((const uint8_t*)mp + mrow0 +               \
                                       (size_t)mqq * SLK + k0_ + 16 * mpt);       \
            }                                                                     \
        } while (0)

    #define WRITE_LDS(KB)                                                         \
        do {                                                                      \
            _Pragma("unroll")                                                     \
            for (int j = 0; j < 4; ++j) {                                         \
                const int flat = (j * 512 + tid) * 4;                             \
                const int kk   = flat >> 7;                                       \
                const int dd2  = (flat & 127) * 2;                                \
                u32x2 w2;                                                         \
                w2.x = cvtpk(kreg[j].x, kreg[j].y);                               \
                w2.y = cvtpk(kreg[j].z, kreg[j].w);                               \
                *(u32x2*)((char*)k_lds + kk * 256 + (dd2 ^ ((kk & 7) << 4))) = w2;\
            }                                                                     \
            {                                                                     \
                char* vrow_ = (char*)vt_lds + vd * 128;                           \
                _Pragma("unroll")                                                 \
                for (int j = 0; j < 4; ++j) {                                     \
                    u32x2 w2;                                                     \
                    w2.x = cvtpk(vreg[4 * j + 0], vreg[4 * j + 1]);               \
                    w2.y = cvtpk(vreg[4 * j + 2], vreg[4 * j + 3]);               \
                    *(u32x2*)(vrow_ + ((32 * vg + 8 * j) ^ swv)) = w2;            \
                }                                                                 \
            }                                                                     \
            if (mmode == 0) {                                                     \
                m_lds[mqq * 4 + mpt] = (uint16_t)pack16(mreg);                    \
            } else {                                                              \
                const size_t e0_ = mrow0 + (size_t)mqq * SLK + (KB) * KVB + 16 * mpt; \
                uint32_t bits = 0;                                                \
                if (mmode == 1) {                                                 \
                    const uint32_t* s_ = (const uint32_t*)mp + e0_;               \
                    for (int j = 0; j < 16; ++j) bits |= (s_[j] ? 1u : 0u) << j;  \
                } else {                                                          \
                    const uint64_t* s_ = (const uint64_t*)mp + e0_;               \
                    for (int j = 0; j < 16; ++j) bits |= (s_[j] ? 1u : 0u) << j;  \
                }                                                                 \
                m_lds[mqq * 4 + mpt] = (uint16_t)bits;                            \
            }                                                                     \
        } while (0)

    // ---- prologue ----
    LOAD_TILE(0);
    WRITE_LDS(0);
    __syncthreads();

    for (int kb = 0; kb < NKB; ++kb) {
        // ---- issue next tile's loads; fly across the compute phase ----
        if (kb + 1 < NKB) LOAD_TILE(kb + 1);
        __builtin_amdgcn_sched_barrier(0);

        // ---- swapped QK^T over this wave's 32-key half, log2 units ----
        f32x16 sacc;
        #pragma unroll
        for (int j = 0; j < 16; ++j) sacc[j] = 0.0f;
        {
            const int row = 32 * th + l31;
            const char* krow = (const char*)k_lds + row * 256;
            const int sw = (row & 7) << 4;
            __builtin_amdgcn_s_setprio(1);
            #pragma unroll
            for (int ks = 0; ks < 8; ++ks) {
                bf16x8 af = *(const bf16x8*)(krow + ((32 * ks + 16 * hi2) ^ sw));
                sacc = __builtin_amdgcn_mfma_f32_32x32x16_bf16(af, qf[ks], sacc, 0, 0, 0);
            }
            __builtin_amdgcn_s_setprio(0);
        }

        // ---- softmax: exp2, mask bits, f32 partial sum, pack bf16 pairs ----
        const uint32_t mq = *(const uint32_t*)(&m_lds[(32 * qg + l31) * 4 + 2 * th]);
        uint32_t pw[8];
        #pragma unroll
        for (int rr = 0; rr < 4; ++rr) {
            const uint32_t mn = (mq >> (8 * rr + 4 * hi2)) & 0xFu;
            float em[4];
            #pragma unroll
            for (int c = 0; c < 4; ++c) {
                const float e = EXP2(sacc[4 * rr + c]);
                em[c] = ((mn >> c) & 1u) ? 0.0f : e;
            }
            psum += (em[0] + em[1]) + (em[2] + em[3]);
            pw[2 * rr]     = cvtpk(em[0], em[1]);
            pw[2 * rr + 1] = cvtpk(em[2], em[3]);
        }

        // ---- publish P half to partner waves (slot-swizzled, conflict-free) ----
        {
            uint32_t* pb = p_lds + wv * 512 + (hi2 * 32 + l31) * 8;
            #pragma unroll
            for (int m = 0; m < 4; ++m) {
                u32x2 w2; w2.x = pw[2 * m]; w2.y = pw[2 * m + 1];
                *(u32x2*)(pb + (m ^ sswz) * 2) = w2;
            }
        }
        __syncthreads();  // barA: P ready

        // ---- PV: O[32q x 64d(th)] += P[32q x 64k] * V[64k x 64d(th)] ----
        #pragma unroll
        for (int kss = 0; kss < 4; ++kss) {
            const int ts  = kss >> 1;       // source key-half wave
            const int kk2 = kss & 1;        // 16-key step within that half
            const int m   = 2 * kk2 + hi2;  // source pw dword pair index
            const uint32_t* ps = p_lds + (qg * 2 + ts) * 512;
            const int so = (m ^ sswz) * 2;
            u32x2 a01 = *(const u32x2*)(ps + l31 * 8 + so);         // writer hi2=0 rows
            u32x2 a23 = *(const u32x2*)(ps + (32 + l31) * 8 + so);  // writer hi2=1 rows
            FragU af;
            af.u[0] = a01.x; af.u[1] = a01.y; af.u[2] = a23.x; af.u[3] = a23.y;
            const int keyb = 32 * kss + 16 * hi2;
            __builtin_amdgcn_s_setprio(1);
            #pragma unroll
            for (int dt2 = 0; dt2 < 2; ++dt2) {
                const int drow = 64 * th + 32 * dt2 + l31;
                const char* vrow = (const char*)vt_lds + drow * 128;
                const int sw8 = (drow & 15) << 3;
                FragU vf;
                *(u32x2*)&vf.u[0] = *(const u32x2*)(vrow + ((keyb)     ^ sw8));
                *(u32x2*)&vf.u[2] = *(const u32x2*)(vrow + ((keyb + 8) ^ sw8));
                oacc[dt2] = __builtin_amdgcn_mfma_f32_32x32x16_bf16(af.v, vf.v, oacc[dt2], 0, 0, 0);
            }
            __builtin_amdgcn_s_setprio(0);
        }
        __syncthreads();  // barB: K/V/P reads done

        // ---- stage next tile (vmcnt drain lands here, fully covered) ----
        if (kb + 1 < NKB) WRITE_LDS(kb + 1);
        __syncthreads();  // barC: tiles ready
    }

    // ---- epilogue: cross-hi2 then cross-wave (th) denominator reduction ----
    psum += __shfl_xor(psum, 32);  // lane q=l31 holds sum over this wave's 32 keys
    float* psb = (float*)p_lds;    // p_lds free after last barC
    if (lane < 32) psb[wv * 32 + l31] = psum;
    __syncthreads();
    const float tot = psb[(qg * 2) * 32 + l31] + psb[(qg * 2 + 1) * 32 + l31];

    float* obase = op + ((size_t)b * SLQ + (size_t)(q0 + 32 * qg)) * DD + 64 * th + l31;
    #pragma unroll
    for (int r = 0; r < 16; ++r) {
        const int qrow = (r & 3) + 8 * (r >> 2) + 4 * hi2;
        const float s  = __shfl(tot, qrow);
        const float rs = 1.0f / s;
        #pragma unroll
        for (int dt2 = 0; dt2 < 2; ++dt2) {
            obase[(size_t)qrow * DD + 32 * dt2] = oacc[dt2][r] * rs;
        }
    }
}

extern "C" void kernel_launch(void* const* d_in, const int* in_sizes, int n_in,
                              void* d_out, int out_size, void* d_ws, size_t ws_size,
                              hipStream_t stream)
{
    const float* q = (const float*)d_in[0];
    const float* k = (const float*)d_in[1];
    const float* v = (const float*)d_in[2];
    const void*  m = d_in[3];
    float*       o = (float*)d_out;
    hipLaunchKernelGGL(attn_fwd, dim3((NB * SLQ) / QTILE), dim3(512), 0, stream,
                       q, k, v, m, o);
}